// Round 21
// baseline (510.496 us; speedup 1.0000x reference)
//
#include <hip/hip_runtime.h>
#include <hip/hip_bf16.h>
#include <math.h>

typedef __attribute__((ext_vector_type(8))) __bf16 bf16x8;
typedef __attribute__((ext_vector_type(4))) float f32x4;
typedef unsigned int uint32;

static constexpr int kC   = 384;
static constexpr int kNH  = 12;
static constexpr int kDH  = 32;
static constexpr int kT   = 64;      // tokens per window
static constexpr int kH   = 64;
static constexpr int kW   = 64;
static constexpr int kDFF = 1536;
static constexpr int kQKV = 1152;    // fused qkv row width
static constexpr long kNTOK = 65536;             // B*H*W
static constexpr long kNT  = kNTOK * kC;         // elements of one (tokens x C) activation

__device__ __forceinline__ float bf_lo(uint32 u){ return __uint_as_float(u << 16); }
__device__ __forceinline__ float bf_hi(uint32 u){ return __uint_as_float(u & 0xffff0000u); }

// fast tanh-form gelu: x*e/(1+e), e = exp2(x*(A + B x^2))
__device__ __forceinline__ float gelu_fast(float x) {
    float x2 = x * x;
    float t  = fmaf(0.102944787f, x2, 2.302208165f);
    float m  = fminf(x * t, 80.0f);               // overflow guard
    float e  = __builtin_amdgcn_exp2f(m);
    float d  = 1.0f + e;
    return x * e * __builtin_amdgcn_rcpf(d);
}

// ---------------- fused weight transposes via LDS tiles (coalesced both sides) ----------------
__global__ __launch_bounds__(256) void k_transpose_all(const float* __restrict__ s0, __bf16* __restrict__ d0,
                                                       const float* __restrict__ s1, __bf16* __restrict__ d1,
                                                       const float* __restrict__ s2, __bf16* __restrict__ d2,
                                                       const float* __restrict__ s3, __bf16* __restrict__ d3)
{
    int bid = blockIdx.x;
    const float* src; __bf16* dst; int K, N;
    if      (bid < 108) {              src = s0; dst = d0; K = 384;  N = 1152; }  // 6x18
    else if (bid < 144) { bid -= 108;  src = s1; dst = d1; K = 384;  N = 384;  }  // 6x6
    else if (bid < 288) { bid -= 144;  src = s2; dst = d2; K = 384;  N = 1536; }  // 6x24
    else                { bid -= 288;  src = s3; dst = d3; K = 1536; N = 384;  }  // 24x6
    const int ntn = N >> 6;
    const int k0 = (bid / ntn) << 6, n0 = (bid % ntn) << 6;

    __shared__ float t[64][65];
    const int c  = threadIdx.x & 63;
    const int r0 = threadIdx.x >> 6;          // 0..3

    #pragma unroll
    for (int i = 0; i < 16; ++i) {
        int r = r0 * 16 + i;
        t[r][c] = src[(size_t)(k0 + r) * N + n0 + c];
    }
    __syncthreads();
    #pragma unroll
    for (int i = 0; i < 16; ++i) {
        int r = r0 * 16 + i;
        dst[(size_t)(n0 + r) * K + k0 + c] = (__bf16)t[c][r];
    }
}

// ---------------- shift2d + window partition + bf16 cast ----------------
__global__ __launch_bounds__(256) void k_shift_window(const float* __restrict__ x,
                                                      __bf16* __restrict__ Aw)
{
    int tid = blockIdx.x * 256 + threadIdx.x;   // 0 .. 65536*48
    int m = tid / 48;
    int g = tid - m * 48;
    int c0 = g * 8;
    int wi = m >> 6, t = m & 63;
    int b = wi >> 6, nh = (wi >> 3) & 7, nw = wi & 7;
    int h = nh * 8 + (t >> 3);
    int w = nw * 8 + (t & 7);
    int q = c0 / 96;
    int sh = h, sw = w;
    bool ok;
    if      (q == 0) { sh = h - 1; ok = (h >= 1);  }
    else if (q == 1) { sh = h + 1; ok = (h <= 62); }
    else if (q == 2) { sw = w - 1; ok = (w >= 1);  }
    else             { sw = w + 1; ok = (w <= 62); }

    __bf16 r[8] __attribute__((aligned(16)));
    if (ok) {
        const float4* src = reinterpret_cast<const float4*>(
            x + (((size_t)b * kH + sh) * kW + sw) * kC + c0);
        float4 v0 = src[0], v1 = src[1];
        r[0] = (__bf16)v0.x; r[1] = (__bf16)v0.y; r[2] = (__bf16)v0.z; r[3] = (__bf16)v0.w;
        r[4] = (__bf16)v1.x; r[5] = (__bf16)v1.y; r[6] = (__bf16)v1.z; r[7] = (__bf16)v1.w;
    } else {
        #pragma unroll
        for (int i = 0; i < 8; ++i) r[i] = (__bf16)0.0f;
    }
    *reinterpret_cast<int4*>(Aw + (size_t)m * kC + c0) = *reinterpret_cast<int4*>(r);
}

// ---------------- bf16 MFMA GEMM (best build): C = A(MxK) * B^T(NxK) ----------------
// Block 256(M)x128(N), 8 waves (512 thr) of 64x64 (4M x 2N).
// A triple-buffered (2 ahead), B double-buffered (1 ahead), counted vmcnt(2).
template<int EPI>
__global__ __launch_bounds__(512) void k_gemm(const __bf16* __restrict__ A,
                                              const __bf16* __restrict__ B,
                                              __bf16* __restrict__ Cout,
                                              int N, int K, int nt)
{
    __shared__ __align__(16) __bf16 As[3][256 * 32];   // 3 x 16 KB
    __shared__ __align__(16) __bf16 Bs[2][128 * 32];   // 2 x  8 KB
    const int tid  = threadIdx.x;
    const int wave = tid >> 6, lane = tid & 63;
    const int g = lane >> 4, qh = lane & 15;

    const int nwg = gridDim.x;
    const int wg  = (blockIdx.x & 7) * (nwg >> 3) + (blockIdx.x >> 3);
    const int nb  = wg % nt, mb = wg / nt;
    const int m0 = mb * 256, n0 = nb * 128;
    const int wr = (wave >> 1) * 64;
    const int wc = (wave & 1) * 64;

    const int sw = ((g ^ ((lane >> 1) & 3)) << 3);

    auto STAGE_A = [&](int buf, int t) {
        const int k0 = t << 5;
        #pragma unroll
        for (int i = 0; i < 2; ++i) {
            int idx = tid + i * 512;
            int row = idx >> 2;
            int gseg = (idx & 3) ^ ((idx >> 3) & 3);
            __builtin_amdgcn_global_load_lds(
                (const __attribute__((address_space(1))) void*)(A + (size_t)(m0 + row) * K + k0 + gseg * 8),
                (__attribute__((address_space(3))) void*)(&As[buf][idx * 8]), 16, 0, 0);
        }
    };
    auto STAGE_B = [&](int buf, int t) {
        const int k0 = t << 5;
        int idx = tid;
        int row = idx >> 2;
        int gseg = (idx & 3) ^ ((idx >> 3) & 3);
        __builtin_amdgcn_global_load_lds(
            (const __attribute__((address_space(1))) void*)(B + (size_t)(n0 + row) * K + k0 + gseg * 8),
            (__attribute__((address_space(3))) void*)(&Bs[buf][idx * 8]), 16, 0, 0);
    };

    f32x4 acc[4][4] = {};
    const int nkt = K >> 5;

    STAGE_A(0, 0);
    __builtin_amdgcn_sched_barrier(0);
    STAGE_B(0, 0);
    __builtin_amdgcn_sched_barrier(0);
    STAGE_A(1, 1);
    __builtin_amdgcn_sched_barrier(0);

    int ca = 0, sa = 2;
    for (int t = 0; t < nkt; ++t) {
        if (t + 1 < nkt) asm volatile("s_waitcnt vmcnt(2)" ::: "memory");
        else             asm volatile("s_waitcnt vmcnt(0)" ::: "memory");
        __builtin_amdgcn_s_barrier();
        __builtin_amdgcn_sched_barrier(0);
        if (t + 1 < nkt) STAGE_B((t + 1) & 1, t + 1);
        __builtin_amdgcn_sched_barrier(0);
        if (t + 2 < nkt) STAGE_A(sa, t + 2);
        __builtin_amdgcn_sched_barrier(0);

        bf16x8 af[4], bfr[4];
        #pragma unroll
        for (int mi = 0; mi < 4; ++mi) {
            int ra = wr + mi * 16 + qh;
            af[mi] = *reinterpret_cast<const bf16x8*>(&As[ca][ra * 32 + sw]);
        }
        #pragma unroll
        for (int ni = 0; ni < 4; ++ni) {
            int rb = wc + ni * 16 + qh;
            bfr[ni] = *reinterpret_cast<const bf16x8*>(&Bs[t & 1][rb * 32 + sw]);
        }
        __builtin_amdgcn_s_setprio(1);
        #pragma unroll
        for (int mi = 0; mi < 4; ++mi)
            #pragma unroll
            for (int ni = 0; ni < 4; ++ni)
                acc[mi][ni] = __builtin_amdgcn_mfma_f32_16x16x32_bf16(af[mi], bfr[ni], acc[mi][ni], 0, 0, 0);
        __builtin_amdgcn_s_setprio(0);

        ca = (ca == 2) ? 0 : ca + 1;
        sa = (sa == 2) ? 0 : sa + 1;
    }

    #pragma unroll
    for (int ni = 0; ni < 4; ++ni) {
        const int col = n0 + wc + ni * 16 + qh;
        #pragma unroll
        for (int mi = 0; mi < 4; ++mi) {
            #pragma unroll
            for (int r = 0; r < 4; ++r) {
                int row = m0 + wr + mi * 16 + (g << 2) + r;
                float v = acc[mi][ni][r];
                if constexpr (EPI == 1) {
                    Cout[(size_t)row * N + col] = (__bf16)v;
                } else {
                    Cout[(size_t)row * N + col] = (__bf16)gelu_fast(v);
                }
            }
        }
    }
}

// ---------------- fused GEMM(N=384) + LayerNorm + residual ----------------
// Block 128(M) x 384(N=full rows), 8 waves (512 thr) as 2M x 4N, wave 64x96.
// Same counted-vmcnt schedule as k_gemm (A 3-buf 2-ahead = 1 load/thr,
// B 2-buf 1-ahead = 3 loads/thr, vmcnt(1) mid-loop). Epilogue computes
// per-row mean/var (in-lane over 6 ni + shfl_xor over qh + 4-wave LDS
// reduce in reused staging LDS) then residual + gamma*normalize.
// LN==1 (outproj): A rows WINDOW order; resid = x fp32 natural; out X1 bf16.
// LN==2 (ffn-down): A rows natural; resid = X1 bf16; out fp32.
template<int LN>
__global__ __launch_bounds__(512) void k_gemm_ln(const __bf16* __restrict__ A,
                                                 const __bf16* __restrict__ B,
                                                 const float* __restrict__ gamma,
                                                 const void* __restrict__ resid,
                                                 void* __restrict__ outp,
                                                 int K)
{
    __shared__ __align__(16) __bf16 As[3][128 * 32];   // 3 x 8 KB
    __shared__ __align__(16) __bf16 Bs[2][384 * 32];   // 2 x 24 KB
    const int tid  = threadIdx.x;
    const int wave = tid >> 6, lane = tid & 63;
    const int g = lane >> 4, qh = lane & 15;

    const int nwg = gridDim.x;                     // 512, %8==0
    const int wg  = (blockIdx.x & 7) * (nwg >> 3) + (blockIdx.x >> 3);
    const int m0 = wg * 128;
    const int wr = (wave >> 2) * 64;               // 0,64
    const int wc = (wave & 3) * 96;                // 0,96,192,288

    const int sw = ((g ^ ((lane >> 1) & 3)) << 3);

    auto STAGE_A = [&](int buf, int t) {   // 128 rows x 4 segs = 512 = 1/thread
        const int k0 = t << 5;
        int idx = tid;
        int row = idx >> 2;
        int gseg = (idx & 3) ^ ((idx >> 3) & 3);
        __builtin_amdgcn_global_load_lds(
            (const __attribute__((address_space(1))) void*)(A + (size_t)(m0 + row) * K + k0 + gseg * 8),
            (__attribute__((address_space(3))) void*)(&As[buf][idx * 8]), 16, 0, 0);
    };
    auto STAGE_B = [&](int buf, int t) {   // 384 rows x 4 segs = 1536 = 3/thread
        const int k0 = t << 5;
        #pragma unroll
        for (int i = 0; i < 3; ++i) {
            int idx = tid + i * 512;
            int row = idx >> 2;
            int gseg = (idx & 3) ^ ((idx >> 3) & 3);
            __builtin_amdgcn_global_load_lds(
                (const __attribute__((address_space(1))) void*)(B + (size_t)row * K + k0 + gseg * 8),
                (__attribute__((address_space(3))) void*)(&Bs[buf][idx * 8]), 16, 0, 0);
        }
    };

    f32x4 acc[4][6] = {};
    const int nkt = K >> 5;

    // prologue queue (oldest first): A(0)=1, B(0)=3, A(1)=1
    STAGE_A(0, 0);
    __builtin_amdgcn_sched_barrier(0);
    STAGE_B(0, 0);
    __builtin_amdgcn_sched_barrier(0);
    STAGE_A(1, 1);
    __builtin_amdgcn_sched_barrier(0);

    int ca = 0, sa = 2;
    for (int t = 0; t < nkt; ++t) {
        // drain A(t)(1)+B(t)(3); leave A(t+1)'s 1 load in flight
        if (t + 1 < nkt) asm volatile("s_waitcnt vmcnt(1)" ::: "memory");
        else             asm volatile("s_waitcnt vmcnt(0)" ::: "memory");
        __builtin_amdgcn_s_barrier();
        __builtin_amdgcn_sched_barrier(0);
        if (t + 1 < nkt) STAGE_B((t + 1) & 1, t + 1);
        __builtin_amdgcn_sched_barrier(0);
        if (t + 2 < nkt) STAGE_A(sa, t + 2);
        __builtin_amdgcn_sched_barrier(0);

        bf16x8 af[4], bfr[6];
        #pragma unroll
        for (int mi = 0; mi < 4; ++mi) {
            int ra = wr + mi * 16 + qh;
            af[mi] = *reinterpret_cast<const bf16x8*>(&As[ca][ra * 32 + sw]);
        }
        #pragma unroll
        for (int ni = 0; ni < 6; ++ni) {
            int rb = wc + ni * 16 + qh;
            bfr[ni] = *reinterpret_cast<const bf16x8*>(&Bs[t & 1][rb * 32 + sw]);
        }
        __builtin_amdgcn_s_setprio(1);
        #pragma unroll
        for (int mi = 0; mi < 4; ++mi)
            #pragma unroll
            for (int ni = 0; ni < 6; ++ni)
                acc[mi][ni] = __builtin_amdgcn_mfma_f32_16x16x32_bf16(af[mi], bfr[ni], acc[mi][ni], 0, 0, 0);
        __builtin_amdgcn_s_setprio(0);

        ca = (ca == 2) ? 0 : ca + 1;
        sa = (sa == 2) ? 0 : sa + 1;
    }

    // ---- LN reduce: reuse staging LDS (all loads drained via vmcnt(0); reads done)
    __syncthreads();
    float* red   = reinterpret_cast<float*>(&As[0][0]);   // [128][4][2] = 4 KB
    float2* stats = reinterpret_cast<float2*>(&Bs[0][0]); // [128] = 1 KB

    #pragma unroll
    for (int mi = 0; mi < 4; ++mi) {
        #pragma unroll
        for (int r = 0; r < 4; ++r) {
            float t1 = 0.f, t2 = 0.f;
            #pragma unroll
            for (int ni = 0; ni < 6; ++ni) {
                float v = acc[mi][ni][r];
                t1 += v; t2 += v * v;
            }
            #pragma unroll
            for (int st = 1; st < 16; st <<= 1) {
                t1 += __shfl_xor(t1, st);
                t2 += __shfl_xor(t2, st);
            }
            if (qh == 0) {
                int row = wr + mi * 16 + (g << 2) + r;   // 0..127
                red[(row * 4 + (wave & 3)) * 2 + 0] = t1;
                red[(row * 4 + (wave & 3)) * 2 + 1] = t2;
            }
        }
    }
    __syncthreads();
    if (tid < 128) {
        float s1 = red[(tid * 4 + 0) * 2] + red[(tid * 4 + 1) * 2] +
                   red[(tid * 4 + 2) * 2] + red[(tid * 4 + 3) * 2];
        float s2 = red[(tid * 4 + 0) * 2 + 1] + red[(tid * 4 + 1) * 2 + 1] +
                   red[(tid * 4 + 2) * 2 + 1] + red[(tid * 4 + 3) * 2 + 1];
        float mean = s1 * (1.0f / 384.0f);
        float var  = s2 * (1.0f / 384.0f) - mean * mean;
        stats[tid] = make_float2(mean, rsqrtf(var + 1e-5f));
    }
    __syncthreads();

    float gcol[6];
    #pragma unroll
    for (int ni = 0; ni < 6; ++ni) gcol[ni] = gamma[wc + ni * 16 + qh];

    #pragma unroll
    for (int mi = 0; mi < 4; ++mi) {
        #pragma unroll
        for (int r = 0; r < 4; ++r) {
            const int rl = wr + mi * 16 + (g << 2) + r;    // 0..127
            const float2 st = stats[rl];
            size_t tok;
            if constexpr (LN == 1) {
                int m = m0 + rl;                  // window order -> natural tok
                int t = m & 63, wi = m >> 6;
                int b = wi >> 6, nh = (wi >> 3) & 7, nw = wi & 7;
                int h = nh * 8 + (t >> 3);
                int w = nw * 8 + (t & 7);
                tok = ((size_t)b << 12) | (h << 6) | w;
            } else {
                tok = (size_t)(m0 + rl);
            }
            #pragma unroll
            for (int ni = 0; ni < 6; ++ni) {
                const int col = wc + ni * 16 + qh;
                float v = (acc[mi][ni][r] - st.x) * st.y * gcol[ni];
                if constexpr (LN == 1) {
                    float xr = ((const float*)resid)[tok * kC + col];
                    ((__bf16*)outp)[tok * kC + col] = (__bf16)(xr + v);
                } else {
                    float xr = (float)((const __bf16*)resid)[tok * kC + col];
                    ((float*)outp)[tok * kC + col] = xr + v;
                }
            }
        }
    }
}

// ---------------- MFMA window attention: one wave per (window, head) ----------------
// qkv is row-major [m][1152]: cols [0,384)=Q, [384,768)=K, [768,1152)=V.
__global__ __launch_bounds__(256) void k_attn(const __bf16* __restrict__ qkv,
                                              __bf16* __restrict__ AO)
{
    __shared__ __bf16 Pl[4][kT * kT];   // 8 KB per wave, XOR-swizzled P tile
    const int wave = threadIdx.x >> 6, lane = threadIdx.x & 63;
    const int pair = blockIdx.x * 4 + wave;          // 0..12287
    const int wi = pair / kNH, hh = pair - wi * kNH;
    const int g = lane >> 4, qh = lane & 15;

    const __bf16* Qp = qkv + (size_t)wi * 64 * kQKV + hh * kDH;   // row stride kQKV
    const __bf16* Kp = Qp + 384;
    const __bf16* Vp = Qp + 768;
    char* Pb = (char*)&Pl[wave][0];

    bf16x8 qa[4], kb[4];
    #pragma unroll
    for (int mi = 0; mi < 4; ++mi)
        qa[mi] = *reinterpret_cast<const bf16x8*>(Qp + (size_t)(mi * 16 + qh) * kQKV + g * 8);
    #pragma unroll
    for (int ni = 0; ni < 4; ++ni)
        kb[ni] = *reinterpret_cast<const bf16x8*>(Kp + (size_t)(ni * 16 + qh) * kQKV + g * 8);

    f32x4 s[4][4] = {};
    #pragma unroll
    for (int mi = 0; mi < 4; ++mi)
        #pragma unroll
        for (int ni = 0; ni < 4; ++ni)
            s[mi][ni] = __builtin_amdgcn_mfma_f32_16x16x32_bf16(qa[mi], kb[ni], s[mi][ni], 0, 0, 0);

    const float scale = 0.17677669529663687f;  // 32^-0.5
    float rmax[4][4], rsum[4][4];
    #pragma unroll
    for (int mi = 0; mi < 4; ++mi)
        #pragma unroll
        for (int r = 0; r < 4; ++r) {
            float a = fmaxf(fmaxf(s[mi][0][r], s[mi][1][r]), fmaxf(s[mi][2][r], s[mi][3][r]));
            #pragma unroll
            for (int st = 1; st < 16; st <<= 1) a = fmaxf(a, __shfl_xor(a, st));
            rmax[mi][r] = a;
        }
    #pragma unroll
    for (int mi = 0; mi < 4; ++mi)
        #pragma unroll
        for (int r = 0; r < 4; ++r) {
            float acc = 0.f;
            #pragma unroll
            for (int ni = 0; ni < 4; ++ni) {
                float p = __expf((s[mi][ni][r] - rmax[mi][r]) * scale);
                s[mi][ni][r] = p;
                acc += p;
            }
            #pragma unroll
            for (int st = 1; st < 16; st <<= 1) acc += __shfl_xor(acc, st);
            rsum[mi][r] = 1.0f / acc;
        }

    #pragma unroll
    for (int mi = 0; mi < 4; ++mi)
        #pragma unroll
        for (int ni = 0; ni < 4; ++ni)
            #pragma unroll
            for (int r = 0; r < 4; ++r) {
                int row = mi * 16 + g * 4 + r;
                int col = ni * 16 + qh;
                uint32 byte = (uint32)((row << 7) | (col << 1)) ^ (uint32)((row & 7) << 4);
                *reinterpret_cast<__bf16*>(Pb + byte) = (__bf16)s[mi][ni][r];
            }

    f32x4 o[4][2] = {};
    #pragma unroll
    for (int kk = 0; kk < 2; ++kk) {
        bf16x8 pa[4], vb[2];
        #pragma unroll
        for (int mi = 0; mi < 4; ++mi) {
            int row = mi * 16 + qh;
            uint32 byte = (uint32)((row << 7) | (kk << 6) | (g << 4)) ^ (uint32)((row & 7) << 4);
            pa[mi] = *reinterpret_cast<const bf16x8*>(Pb + byte);
        }
        #pragma unroll
        for (int n2 = 0; n2 < 2; ++n2) {
            __bf16 tmp[8];
            #pragma unroll
            for (int j = 0; j < 8; ++j)
                tmp[j] = Vp[(size_t)(kk * 32 + g * 8 + j) * kQKV + n2 * 16 + qh];
            vb[n2] = *reinterpret_cast<const bf16x8*>(tmp);
        }
        #pragma unroll
        for (int mi = 0; mi < 4; ++mi)
            #pragma unroll
            for (int n2 = 0; n2 < 2; ++n2)
                o[mi][n2] = __builtin_amdgcn_mfma_f32_16x16x32_bf16(pa[mi], vb[n2], o[mi][n2], 0, 0, 0);
    }

    #pragma unroll
    for (int mi = 0; mi < 4; ++mi)
        #pragma unroll
        for (int n2 = 0; n2 < 2; ++n2)
            #pragma unroll
            for (int r = 0; r < 4; ++r) {
                int row = mi * 16 + g * 4 + r;
                AO[((size_t)wi * 64 + row) * kC + hh * kDH + n2 * 16 + qh] =
                    (__bf16)(o[mi][n2][r] * rsum[mi][r]);
            }
}

extern "C" void kernel_launch(void* const* d_in, const int* in_sizes, int n_in,
                              void* d_out, int out_size, void* d_ws, size_t ws_size,
                              hipStream_t stream) {
    const float* x    = (const float*)d_in[0];
    const float* wqkv = (const float*)d_in[1];
    const float* wout = (const float*)d_in[2];
    const float* g_at = (const float*)d_in[3];
    const float* w1   = (const float*)d_in[4];
    const float* w2   = (const float*)d_in[5];
    const float* g_ff = (const float*)d_in[6];
    float* out = (float*)d_out;

    char* ws = (char*)d_ws;
    size_t off = 0;
    auto alloc = [&](size_t bytes) { size_t o = off; off += (bytes + 255) & ~(size_t)255; return o; };
    __bf16* WqkvT = (__bf16*)(ws + alloc((size_t)1152 * 384 * 2));
    __bf16* WoutT = (__bf16*)(ws + alloc((size_t)384 * 384 * 2));
    __bf16* W1T   = (__bf16*)(ws + alloc((size_t)1536 * 384 * 2));
    __bf16* W2T   = (__bf16*)(ws + alloc((size_t)384 * 1536 * 2));
    __bf16* R1    = (__bf16*)(ws + alloc((size_t)kNTOK * kDFF * 2));  // qkv rows (1152) / FFN hidden
    __bf16* R2    = (__bf16*)(ws + alloc((size_t)kNT * 2));           // Aw -> AO
    __bf16* R3    = (__bf16*)(ws + alloc((size_t)kNT * 2));           // X1 (bf16, natural)

    // all four weight transposes, LDS-tiled (432 tiles of 64x64)
    k_transpose_all<<<dim3(432), 256, 0, stream>>>(wqkv, WqkvT, wout, WoutT, w1, W1T, w2, W2T);

    // shift2d + window partition
    k_shift_window<<<dim3(12288), 256, 0, stream>>>(x, R2);

    // qkv projection (plain row-major [m][1152] output): M=65536, N=1152, K=384
    k_gemm<1><<<dim3(256 * 9), 512, 0, stream>>>(R2, WqkvT, R1, 1152, 384, 9);

    // window attention (MFMA, reads interleaved qkv rows)
    k_attn<<<dim3(3072), 256, 0, stream>>>(R1, R2);

    // outproj + LN + residual (fused): X1 = x + LN(AO @ WoutT), K=384
    k_gemm_ln<1><<<dim3(512), 512, 0, stream>>>(R2, WoutT, g_at, x, R3, 384);

    // FFN up + gelu: N=1536, K=384 (reads X1 natural order)
    k_gemm<2><<<dim3(256 * 12), 512, 0, stream>>>(R3, W1T, R1, 1536, 384, 12);

    // FFN down + LN + residual (fused): out = X1 + LN(H @ W2T), K=1536
    k_gemm_ln<2><<<dim3(512), 512, 0, stream>>>(R1, W2T, g_ff, R3, out, 1536);
}

// Round 22
// 500.330 us; speedup vs baseline: 1.0203x; 1.0203x over previous
//
#include <hip/hip_runtime.h>
#include <hip/hip_bf16.h>
#include <math.h>

typedef __attribute__((ext_vector_type(8))) __bf16 bf16x8;
typedef __attribute__((ext_vector_type(4))) float f32x4;
typedef unsigned int uint32;

static constexpr int kC   = 384;
static constexpr int kNH  = 12;
static constexpr int kDH  = 32;
static constexpr int kT   = 64;      // tokens per window
static constexpr int kH   = 64;
static constexpr int kW   = 64;
static constexpr int kDFF = 1536;
static constexpr int kQKV = 1152;    // fused qkv row width
static constexpr long kNTOK = 65536;             // B*H*W
static constexpr long kNT  = kNTOK * kC;         // elements of one (tokens x C) activation

__device__ __forceinline__ float bf_lo(uint32 u){ return __uint_as_float(u << 16); }
__device__ __forceinline__ float bf_hi(uint32 u){ return __uint_as_float(u & 0xffff0000u); }

// fast tanh-form gelu: x*e/(1+e), e = exp2(x*(A + B x^2))
__device__ __forceinline__ float gelu_fast(float x) {
    float x2 = x * x;
    float t  = fmaf(0.102944787f, x2, 2.302208165f);
    float m  = fminf(x * t, 80.0f);               // overflow guard
    float e  = __builtin_amdgcn_exp2f(m);
    float d  = 1.0f + e;
    return x * e * __builtin_amdgcn_rcpf(d);
}

// ---------------- fused weight transposes via LDS tiles (coalesced both sides) ----------------
// K x N fp32 -> N x K bf16, 64x64 tiles, one launch for all four weights.
__global__ __launch_bounds__(256) void k_transpose_all(const float* __restrict__ s0, __bf16* __restrict__ d0,
                                                       const float* __restrict__ s1, __bf16* __restrict__ d1,
                                                       const float* __restrict__ s2, __bf16* __restrict__ d2,
                                                       const float* __restrict__ s3, __bf16* __restrict__ d3)
{
    int bid = blockIdx.x;
    const float* src; __bf16* dst; int K, N;
    if      (bid < 108) {              src = s0; dst = d0; K = 384;  N = 1152; }  // 6x18
    else if (bid < 144) { bid -= 108;  src = s1; dst = d1; K = 384;  N = 384;  }  // 6x6
    else if (bid < 288) { bid -= 144;  src = s2; dst = d2; K = 384;  N = 1536; }  // 6x24
    else                { bid -= 288;  src = s3; dst = d3; K = 1536; N = 384;  }  // 24x6
    const int ntn = N >> 6;
    const int k0 = (bid / ntn) << 6, n0 = (bid % ntn) << 6;

    __shared__ float t[64][65];
    const int c  = threadIdx.x & 63;
    const int r0 = threadIdx.x >> 6;          // 0..3

    #pragma unroll
    for (int i = 0; i < 16; ++i) {
        int r = r0 * 16 + i;
        t[r][c] = src[(size_t)(k0 + r) * N + n0 + c];   // coalesced 256B/wave reads
    }
    __syncthreads();
    #pragma unroll
    for (int i = 0; i < 16; ++i) {
        int r = r0 * 16 + i;
        dst[(size_t)(n0 + r) * K + k0 + c] = (__bf16)t[c][r];  // coalesced bf16 writes; pad-65 column read
    }
}

// ---------------- shift2d + window partition + bf16 cast ----------------
__global__ __launch_bounds__(256) void k_shift_window(const float* __restrict__ x,
                                                      __bf16* __restrict__ Aw)
{
    int tid = blockIdx.x * 256 + threadIdx.x;   // 0 .. 65536*48
    int m = tid / 48;
    int g = tid - m * 48;
    int c0 = g * 8;
    int wi = m >> 6, t = m & 63;
    int b = wi >> 6, nh = (wi >> 3) & 7, nw = wi & 7;
    int h = nh * 8 + (t >> 3);
    int w = nw * 8 + (t & 7);
    int q = c0 / 96;
    int sh = h, sw = w;
    bool ok;
    if      (q == 0) { sh = h - 1; ok = (h >= 1);  }
    else if (q == 1) { sh = h + 1; ok = (h <= 62); }
    else if (q == 2) { sw = w - 1; ok = (w >= 1);  }
    else             { sw = w + 1; ok = (w <= 62); }

    __bf16 r[8] __attribute__((aligned(16)));
    if (ok) {
        const float4* src = reinterpret_cast<const float4*>(
            x + (((size_t)b * kH + sh) * kW + sw) * kC + c0);
        float4 v0 = src[0], v1 = src[1];
        r[0] = (__bf16)v0.x; r[1] = (__bf16)v0.y; r[2] = (__bf16)v0.z; r[3] = (__bf16)v0.w;
        r[4] = (__bf16)v1.x; r[5] = (__bf16)v1.y; r[6] = (__bf16)v1.z; r[7] = (__bf16)v1.w;
    } else {
        #pragma unroll
        for (int i = 0; i < 8; ++i) r[i] = (__bf16)0.0f;
    }
    *reinterpret_cast<int4*>(Aw + (size_t)m * kC + c0) = *reinterpret_cast<int4*>(r);
}

// ---------------- bf16 MFMA GEMM (best measured build): C = A(MxK) * B^T(NxK) ----------------
// Block 256(M)x128(N), 8 waves (512 thr) of 64x64 (4M x 2N).
// A triple-buffered (staged 2 ahead), B double-buffered (1 ahead), counted
// vmcnt(2). Both-sides swizzle, XCD chunking. EPI: 1 = plain bf16 store,
// 2 = gelu + store.
template<int EPI>
__global__ __launch_bounds__(512) void k_gemm(const __bf16* __restrict__ A,
                                              const __bf16* __restrict__ B,
                                              __bf16* __restrict__ Cout,
                                              int N, int K, int nt)
{
    __shared__ __align__(16) __bf16 As[3][256 * 32];   // 3 x 16 KB
    __shared__ __align__(16) __bf16 Bs[2][128 * 32];   // 2 x  8 KB
    const int tid  = threadIdx.x;
    const int wave = tid >> 6, lane = tid & 63;
    const int g = lane >> 4, qh = lane & 15;

    const int nwg = gridDim.x;
    const int wg  = (blockIdx.x & 7) * (nwg >> 3) + (blockIdx.x >> 3);
    const int nb  = wg % nt, mb = wg / nt;
    const int m0 = mb * 256, n0 = nb * 128;
    const int wr = (wave >> 1) * 64;      // 0,64,128,192
    const int wc = (wave & 1) * 64;       // 0,64

    const int sw = ((g ^ ((lane >> 1) & 3)) << 3);

    auto STAGE_A = [&](int buf, int t) {   // 2 loads per thread
        const int k0 = t << 5;
        #pragma unroll
        for (int i = 0; i < 2; ++i) {      // A: 256 rows x 4 segs = 1024
            int idx = tid + i * 512;
            int row = idx >> 2;
            int gseg = (idx & 3) ^ ((idx >> 3) & 3);
            __builtin_amdgcn_global_load_lds(
                (const __attribute__((address_space(1))) void*)(A + (size_t)(m0 + row) * K + k0 + gseg * 8),
                (__attribute__((address_space(3))) void*)(&As[buf][idx * 8]), 16, 0, 0);
        }
    };
    auto STAGE_B = [&](int buf, int t) {   // 1 load per thread
        const int k0 = t << 5;
        int idx = tid;                      // B: 128 rows x 4 segs = 512
        int row = idx >> 2;
        int gseg = (idx & 3) ^ ((idx >> 3) & 3);
        __builtin_amdgcn_global_load_lds(
            (const __attribute__((address_space(1))) void*)(B + (size_t)(n0 + row) * K + k0 + gseg * 8),
            (__attribute__((address_space(3))) void*)(&Bs[buf][idx * 8]), 16, 0, 0);
    };

    f32x4 acc[4][4] = {};
    const int nkt = K >> 5;

    // prologue: queue order (oldest first) = A(0),B(0),A(1)
    STAGE_A(0, 0);
    __builtin_amdgcn_sched_barrier(0);
    STAGE_B(0, 0);
    __builtin_amdgcn_sched_barrier(0);
    STAGE_A(1, 1);
    __builtin_amdgcn_sched_barrier(0);

    int ca = 0, sa = 2;    // compute-A buffer, stage-A target
    for (int t = 0; t < nkt; ++t) {
        // drain A(t)+B(t); leave A(t+1)'s 2 loads in flight
        if (t + 1 < nkt) asm volatile("s_waitcnt vmcnt(2)" ::: "memory");
        else             asm volatile("s_waitcnt vmcnt(0)" ::: "memory");
        __builtin_amdgcn_s_barrier();
        __builtin_amdgcn_sched_barrier(0);
        // issue order matters for vmcnt counting: B(t+1) first, then A(t+2)
        if (t + 1 < nkt) STAGE_B((t + 1) & 1, t + 1);
        __builtin_amdgcn_sched_barrier(0);
        if (t + 2 < nkt) STAGE_A(sa, t + 2);
        __builtin_amdgcn_sched_barrier(0);

        bf16x8 af[4], bfr[4];
        #pragma unroll
        for (int mi = 0; mi < 4; ++mi) {
            int ra = wr + mi * 16 + qh;
            af[mi] = *reinterpret_cast<const bf16x8*>(&As[ca][ra * 32 + sw]);
        }
        #pragma unroll
        for (int ni = 0; ni < 4; ++ni) {
            int rb = wc + ni * 16 + qh;
            bfr[ni] = *reinterpret_cast<const bf16x8*>(&Bs[t & 1][rb * 32 + sw]);
        }
        __builtin_amdgcn_s_setprio(1);
        #pragma unroll
        for (int mi = 0; mi < 4; ++mi)
            #pragma unroll
            for (int ni = 0; ni < 4; ++ni)
                acc[mi][ni] = __builtin_amdgcn_mfma_f32_16x16x32_bf16(af[mi], bfr[ni], acc[mi][ni], 0, 0, 0);
        __builtin_amdgcn_s_setprio(0);

        ca = (ca == 2) ? 0 : ca + 1;
        sa = (sa == 2) ? 0 : sa + 1;
    }

    #pragma unroll
    for (int ni = 0; ni < 4; ++ni) {
        const int col = n0 + wc + ni * 16 + qh;
        #pragma unroll
        for (int mi = 0; mi < 4; ++mi) {
            #pragma unroll
            for (int r = 0; r < 4; ++r) {
                int row = m0 + wr + mi * 16 + (g << 2) + r;
                float v = acc[mi][ni][r];
                if constexpr (EPI == 1) {
                    Cout[(size_t)row * N + col] = (__bf16)v;
                } else {
                    Cout[(size_t)row * N + col] = (__bf16)gelu_fast(v);
                }
            }
        }
    }
}

// ---------------- MFMA window attention: one wave per (window, head) ----------------
// qkv is row-major [m][1152]: cols [0,384)=Q heads, [384,768)=K, [768,1152)=V;
// within each third, head hh occupies cols hh*32..hh*32+31. Row m = wi*64 + t.
__global__ __launch_bounds__(256) void k_attn(const __bf16* __restrict__ qkv,
                                              __bf16* __restrict__ AO)
{
    __shared__ __bf16 Pl[4][kT * kT];   // 8 KB per wave, XOR-swizzled P tile
    const int wave = threadIdx.x >> 6, lane = threadIdx.x & 63;
    const int pair = blockIdx.x * 4 + wave;          // 0..12287
    const int wi = pair / kNH, hh = pair - wi * kNH;
    const int g = lane >> 4, qh = lane & 15;

    const __bf16* Qp = qkv + (size_t)wi * 64 * kQKV + hh * kDH;   // row stride kQKV
    const __bf16* Kp = Qp + 384;
    const __bf16* Vp = Qp + 768;
    char* Pb = (char*)&Pl[wave][0];

    bf16x8 qa[4], kb[4];
    #pragma unroll
    for (int mi = 0; mi < 4; ++mi)
        qa[mi] = *reinterpret_cast<const bf16x8*>(Qp + (size_t)(mi * 16 + qh) * kQKV + g * 8);
    #pragma unroll
    for (int ni = 0; ni < 4; ++ni)
        kb[ni] = *reinterpret_cast<const bf16x8*>(Kp + (size_t)(ni * 16 + qh) * kQKV + g * 8);

    f32x4 s[4][4] = {};
    #pragma unroll
    for (int mi = 0; mi < 4; ++mi)
        #pragma unroll
        for (int ni = 0; ni < 4; ++ni)
            s[mi][ni] = __builtin_amdgcn_mfma_f32_16x16x32_bf16(qa[mi], kb[ni], s[mi][ni], 0, 0, 0);

    const float scale = 0.17677669529663687f;  // 32^-0.5
    float rmax[4][4], rsum[4][4];
    #pragma unroll
    for (int mi = 0; mi < 4; ++mi)
        #pragma unroll
        for (int r = 0; r < 4; ++r) {
            float a = fmaxf(fmaxf(s[mi][0][r], s[mi][1][r]), fmaxf(s[mi][2][r], s[mi][3][r]));
            #pragma unroll
            for (int st = 1; st < 16; st <<= 1) a = fmaxf(a, __shfl_xor(a, st));
            rmax[mi][r] = a;
        }
    #pragma unroll
    for (int mi = 0; mi < 4; ++mi)
        #pragma unroll
        for (int r = 0; r < 4; ++r) {
            float acc = 0.f;
            #pragma unroll
            for (int ni = 0; ni < 4; ++ni) {
                float p = __expf((s[mi][ni][r] - rmax[mi][r]) * scale);
                s[mi][ni][r] = p;
                acc += p;
            }
            #pragma unroll
            for (int st = 1; st < 16; st <<= 1) acc += __shfl_xor(acc, st);
            rsum[mi][r] = 1.0f / acc;
        }

    #pragma unroll
    for (int mi = 0; mi < 4; ++mi)
        #pragma unroll
        for (int ni = 0; ni < 4; ++ni)
            #pragma unroll
            for (int r = 0; r < 4; ++r) {
                int row = mi * 16 + g * 4 + r;
                int col = ni * 16 + qh;
                uint32 byte = (uint32)((row << 7) | (col << 1)) ^ (uint32)((row & 7) << 4);
                *reinterpret_cast<__bf16*>(Pb + byte) = (__bf16)s[mi][ni][r];
            }

    f32x4 o[4][2] = {};
    #pragma unroll
    for (int kk = 0; kk < 2; ++kk) {
        bf16x8 pa[4], vb[2];
        #pragma unroll
        for (int mi = 0; mi < 4; ++mi) {
            int row = mi * 16 + qh;
            uint32 byte = (uint32)((row << 7) | (kk << 6) | (g << 4)) ^ (uint32)((row & 7) << 4);
            pa[mi] = *reinterpret_cast<const bf16x8*>(Pb + byte);
        }
        #pragma unroll
        for (int n2 = 0; n2 < 2; ++n2) {
            __bf16 tmp[8];
            #pragma unroll
            for (int j = 0; j < 8; ++j)
                tmp[j] = Vp[(size_t)(kk * 32 + g * 8 + j) * kQKV + n2 * 16 + qh];
            vb[n2] = *reinterpret_cast<const bf16x8*>(tmp);
        }
        #pragma unroll
        for (int mi = 0; mi < 4; ++mi)
            #pragma unroll
            for (int n2 = 0; n2 < 2; ++n2)
                o[mi][n2] = __builtin_amdgcn_mfma_f32_16x16x32_bf16(pa[mi], vb[n2], o[mi][n2], 0, 0, 0);
    }

    #pragma unroll
    for (int mi = 0; mi < 4; ++mi)
        #pragma unroll
        for (int n2 = 0; n2 < 2; ++n2)
            #pragma unroll
            for (int r = 0; r < 4; ++r) {
                int row = mi * 16 + g * 4 + r;
                AO[((size_t)wi * 64 + row) * kC + hh * kDH + n2 * 16 + qh] =
                    (__bf16)(o[mi][n2][r] * rsum[mi][r]);
            }
}

// ---------------- LN(no-bias) + residual, window-order input (vectorized) ----------------
__global__ __launch_bounds__(256) void k_ln_res1(const __bf16* __restrict__ P,
                                                 const float* __restrict__ x,
                                                 const float* __restrict__ gamma,
                                                 __bf16* __restrict__ X1)
{
    const int wave = threadIdx.x >> 6, lane = threadIdx.x & 63;
    const int tok = blockIdx.x * 4 + wave;     // natural: b*4096 + h*64 + w
    const int b = tok >> 12, hw = tok & 4095, h = hw >> 6, w = hw & 63;
    const int m = (((b << 6) | ((h >> 3) << 3) | (w >> 3)) << 6) | (((h & 7) << 3) | (w & 7));

    const uint32* Pv = reinterpret_cast<const uint32*>(P + (size_t)m * kC);
    float p[6]; float sum = 0.f, sq = 0.f;
    #pragma unroll
    for (int i = 0; i < 3; ++i) {
        uint32 u = Pv[lane + i * 64];
        float a = bf_lo(u), bb = bf_hi(u);
        p[2 * i] = a; p[2 * i + 1] = bb;
        sum += a + bb; sq += a * a + bb * bb;
    }
    #pragma unroll
    for (int off = 32; off; off >>= 1) { sum += __shfl_xor(sum, off); sq += __shfl_xor(sq, off); }
    float mean = sum * (1.0f / kC);
    float var  = sq * (1.0f / kC) - mean * mean;
    float rs   = rsqrtf(var + 1e-5f);

    const float2* xv = reinterpret_cast<const float2*>(x + (size_t)tok * kC);
    const float2* gv = reinterpret_cast<const float2*>(gamma);
    uint32* Xv = reinterpret_cast<uint32*>(X1 + (size_t)tok * kC);
    #pragma unroll
    for (int i = 0; i < 3; ++i) {
        int idx = lane + i * 64;
        float2 xr = xv[idx];
        float2 gg = gv[idx];
        float v0 = xr.x + (p[2 * i]     - mean) * rs * gg.x;
        float v1 = xr.y + (p[2 * i + 1] - mean) * rs * gg.y;
        __bf16 t2[2] __attribute__((aligned(4)));
        t2[0] = (__bf16)v0; t2[1] = (__bf16)v1;
        Xv[idx] = *reinterpret_cast<uint32*>(t2);
    }
}

// ---------------- LN(no-bias) + residual, natural order, fp32 out (vectorized) ----------------
__global__ __launch_bounds__(256) void k_ln_res2(const __bf16* __restrict__ F,
                                                 const __bf16* __restrict__ X1,
                                                 const float* __restrict__ gamma,
                                                 float* __restrict__ out)
{
    const int wave = threadIdx.x >> 6, lane = threadIdx.x & 63;
    const size_t tok = blockIdx.x * 4 + wave;

    const uint32* Fv = reinterpret_cast<const uint32*>(F + tok * kC);
    float f[6]; float sum = 0.f, sq = 0.f;
    #pragma unroll
    for (int i = 0; i < 3; ++i) {
        uint32 u = Fv[lane + i * 64];
        float a = bf_lo(u), bb = bf_hi(u);
        f[2 * i] = a; f[2 * i + 1] = bb;
        sum += a + bb; sq += a * a + bb * bb;
    }
    #pragma unroll
    for (int off = 32; off; off >>= 1) { sum += __shfl_xor(sum, off); sq += __shfl_xor(sq, off); }
    float mean = sum * (1.0f / kC);
    float var  = sq * (1.0f / kC) - mean * mean;
    float rs   = rsqrtf(var + 1e-5f);

    const uint32* Xv = reinterpret_cast<const uint32*>(X1 + tok * kC);
    const float2* gv = reinterpret_cast<const float2*>(gamma);
    float2* ov = reinterpret_cast<float2*>(out + tok * kC);
    #pragma unroll
    for (int i = 0; i < 3; ++i) {
        int idx = lane + i * 64;
        uint32 xr = Xv[idx];
        float2 gg = gv[idx];
        float2 o2;
        o2.x = bf_lo(xr) + (f[2 * i]     - mean) * rs * gg.x;
        o2.y = bf_hi(xr) + (f[2 * i + 1] - mean) * rs * gg.y;
        ov[idx] = o2;
    }
}

extern "C" void kernel_launch(void* const* d_in, const int* in_sizes, int n_in,
                              void* d_out, int out_size, void* d_ws, size_t ws_size,
                              hipStream_t stream) {
    const float* x    = (const float*)d_in[0];
    const float* wqkv = (const float*)d_in[1];
    const float* wout = (const float*)d_in[2];
    const float* g_at = (const float*)d_in[3];
    const float* w1   = (const float*)d_in[4];
    const float* w2   = (const float*)d_in[5];
    const float* g_ff = (const float*)d_in[6];
    float* out = (float*)d_out;

    char* ws = (char*)d_ws;
    size_t off = 0;
    auto alloc = [&](size_t bytes) { size_t o = off; off += (bytes + 255) & ~(size_t)255; return o; };
    __bf16* WqkvT = (__bf16*)(ws + alloc((size_t)1152 * 384 * 2));
    __bf16* WoutT = (__bf16*)(ws + alloc((size_t)384 * 384 * 2));
    __bf16* W1T   = (__bf16*)(ws + alloc((size_t)1536 * 384 * 2));
    __bf16* W2T   = (__bf16*)(ws + alloc((size_t)384 * 1536 * 2));
    __bf16* R1    = (__bf16*)(ws + alloc((size_t)kNTOK * kDFF * 2));  // qkv rows (1152) / FFN hidden
    __bf16* R2    = (__bf16*)(ws + alloc((size_t)kNT * 2));           // Aw -> AO -> X1
    __bf16* R3    = (__bf16*)(ws + alloc((size_t)kNT * 2));           // P -> F

    // all four weight transposes, LDS-tiled (432 tiles of 64x64)
    k_transpose_all<<<dim3(432), 256, 0, stream>>>(wqkv, WqkvT, wout, WoutT, w1, W1T, w2, W2T);

    // shift2d + window partition
    k_shift_window<<<dim3(12288), 256, 0, stream>>>(x, R2);

    // qkv projection (plain row-major [m][1152] output): M=65536, N=1152, K=384
    k_gemm<1><<<dim3(256 * 9), 512, 0, stream>>>(R2, WqkvT, R1, 1152, 384, 9);

    // window attention (MFMA, reads interleaved qkv rows)
    k_attn<<<dim3(3072), 256, 0, stream>>>(R1, R2);

    // output projection: N=384, K=384
    k_gemm<1><<<dim3(256 * 3), 512, 0, stream>>>(R2, WoutT, R3, 384, 384, 3);

    // x1 = x + LN(attn)
    k_ln_res1<<<dim3(16384), 256, 0, stream>>>(R3, x, g_at, R2);

    // FFN up + gelu: N=1536, K=384
    k_gemm<2><<<dim3(256 * 12), 512, 0, stream>>>(R2, W1T, R1, 1536, 384, 12);

    // FFN down: N=384, K=1536
    k_gemm<1><<<dim3(256 * 3), 512, 0, stream>>>(R1, W2T, R3, 384, 1536, 3);

    // out = x1 + LN(f)
    k_ln_res2<<<dim3(16384), 256, 0, stream>>>(R3, R2, g_ff, out);
}

// Round 23
// 496.767 us; speedup vs baseline: 1.0276x; 1.0072x over previous
//
#include <hip/hip_runtime.h>
#include <hip/hip_bf16.h>
#include <math.h>

typedef __attribute__((ext_vector_type(8))) __bf16 bf16x8;
typedef __attribute__((ext_vector_type(4))) float f32x4;
typedef unsigned int uint32;

static constexpr int kC   = 384;
static constexpr int kNH  = 12;
static constexpr int kDH  = 32;
static constexpr int kT   = 64;      // tokens per window
static constexpr int kH   = 64;
static constexpr int kW   = 64;
static constexpr int kDFF = 1536;
static constexpr int kQKV = 1152;    // fused qkv row width
static constexpr long kNTOK = 65536;             // B*H*W
static constexpr long kNT  = kNTOK * kC;         // elements of one (tokens x C) activation

__device__ __forceinline__ float bf_lo(uint32 u){ return __uint_as_float(u << 16); }
__device__ __forceinline__ float bf_hi(uint32 u){ return __uint_as_float(u & 0xffff0000u); }

// fast tanh-form gelu: x*e/(1+e), e = exp2(x*(A + B x^2))
__device__ __forceinline__ float gelu_fast(float x) {
    float x2 = x * x;
    float t  = fmaf(0.102944787f, x2, 2.302208165f);
    float m  = fminf(x * t, 80.0f);               // overflow guard
    float e  = __builtin_amdgcn_exp2f(m);
    float d  = 1.0f + e;
    return x * e * __builtin_amdgcn_rcpf(d);
}

// ---------------- fused weight transposes via LDS tiles (coalesced both sides) ----------------
// K x N fp32 -> N x K bf16, 64x64 tiles, one launch for all four weights.
__global__ __launch_bounds__(256) void k_transpose_all(const float* __restrict__ s0, __bf16* __restrict__ d0,
                                                       const float* __restrict__ s1, __bf16* __restrict__ d1,
                                                       const float* __restrict__ s2, __bf16* __restrict__ d2,
                                                       const float* __restrict__ s3, __bf16* __restrict__ d3)
{
    int bid = blockIdx.x;
    const float* src; __bf16* dst; int K, N;
    if      (bid < 108) {              src = s0; dst = d0; K = 384;  N = 1152; }  // 6x18
    else if (bid < 144) { bid -= 108;  src = s1; dst = d1; K = 384;  N = 384;  }  // 6x6
    else if (bid < 288) { bid -= 144;  src = s2; dst = d2; K = 384;  N = 1536; }  // 6x24
    else                { bid -= 288;  src = s3; dst = d3; K = 1536; N = 384;  }  // 24x6
    const int ntn = N >> 6;
    const int k0 = (bid / ntn) << 6, n0 = (bid % ntn) << 6;

    __shared__ float t[64][65];
    const int c  = threadIdx.x & 63;
    const int r0 = threadIdx.x >> 6;          // 0..3

    #pragma unroll
    for (int i = 0; i < 16; ++i) {
        int r = r0 * 16 + i;
        t[r][c] = src[(size_t)(k0 + r) * N + n0 + c];   // coalesced 256B/wave reads
    }
    __syncthreads();
    #pragma unroll
    for (int i = 0; i < 16; ++i) {
        int r = r0 * 16 + i;
        dst[(size_t)(n0 + r) * K + k0 + c] = (__bf16)t[c][r];  // coalesced bf16 writes; pad-65 column read
    }
}

// ---------------- shift2d + window partition + bf16 cast ----------------
__global__ __launch_bounds__(256) void k_shift_window(const float* __restrict__ x,
                                                      __bf16* __restrict__ Aw)
{
    int tid = blockIdx.x * 256 + threadIdx.x;   // 0 .. 65536*48
    int m = tid / 48;
    int g = tid - m * 48;
    int c0 = g * 8;
    int wi = m >> 6, t = m & 63;
    int b = wi >> 6, nh = (wi >> 3) & 7, nw = wi & 7;
    int h = nh * 8 + (t >> 3);
    int w = nw * 8 + (t & 7);
    int q = c0 / 96;
    int sh = h, sw = w;
    bool ok;
    if      (q == 0) { sh = h - 1; ok = (h >= 1);  }
    else if (q == 1) { sh = h + 1; ok = (h <= 62); }
    else if (q == 2) { sw = w - 1; ok = (w >= 1);  }
    else             { sw = w + 1; ok = (w <= 62); }

    __bf16 r[8] __attribute__((aligned(16)));
    if (ok) {
        const float4* src = reinterpret_cast<const float4*>(
            x + (((size_t)b * kH + sh) * kW + sw) * kC + c0);
        float4 v0 = src[0], v1 = src[1];
        r[0] = (__bf16)v0.x; r[1] = (__bf16)v0.y; r[2] = (__bf16)v0.z; r[3] = (__bf16)v0.w;
        r[4] = (__bf16)v1.x; r[5] = (__bf16)v1.y; r[6] = (__bf16)v1.z; r[7] = (__bf16)v1.w;
    } else {
        #pragma unroll
        for (int i = 0; i < 8; ++i) r[i] = (__bf16)0.0f;
    }
    *reinterpret_cast<int4*>(Aw + (size_t)m * kC + c0) = *reinterpret_cast<int4*>(r);
}

// ---------------- bf16 MFMA GEMM (best measured build): C = A(MxK) * B^T(NxK) ----------------
// Block 256(M)x128(N), 8 waves (512 thr) of 64x64 (4M x 2N).
// A triple-buffered (staged 2 ahead), B double-buffered (1 ahead), counted
// vmcnt(2). Both-sides swizzle, XCD chunking. EPI: 1 = plain bf16 store,
// 2 = gelu + store.
template<int EPI>
__global__ __launch_bounds__(512) void k_gemm(const __bf16* __restrict__ A,
                                              const __bf16* __restrict__ B,
                                              __bf16* __restrict__ Cout,
                                              int N, int K, int nt)
{
    __shared__ __align__(16) __bf16 As[3][256 * 32];   // 3 x 16 KB
    __shared__ __align__(16) __bf16 Bs[2][128 * 32];   // 2 x  8 KB
    const int tid  = threadIdx.x;
    const int wave = tid >> 6, lane = tid & 63;
    const int g = lane >> 4, qh = lane & 15;

    const int nwg = gridDim.x;
    const int wg  = (blockIdx.x & 7) * (nwg >> 3) + (blockIdx.x >> 3);
    const int nb  = wg % nt, mb = wg / nt;
    const int m0 = mb * 256, n0 = nb * 128;
    const int wr = (wave >> 1) * 64;      // 0,64,128,192
    const int wc = (wave & 1) * 64;       // 0,64

    const int sw = ((g ^ ((lane >> 1) & 3)) << 3);

    auto STAGE_A = [&](int buf, int t) {   // 2 loads per thread
        const int k0 = t << 5;
        #pragma unroll
        for (int i = 0; i < 2; ++i) {      // A: 256 rows x 4 segs = 1024
            int idx = tid + i * 512;
            int row = idx >> 2;
            int gseg = (idx & 3) ^ ((idx >> 3) & 3);
            __builtin_amdgcn_global_load_lds(
                (const __attribute__((address_space(1))) void*)(A + (size_t)(m0 + row) * K + k0 + gseg * 8),
                (__attribute__((address_space(3))) void*)(&As[buf][idx * 8]), 16, 0, 0);
        }
    };
    auto STAGE_B = [&](int buf, int t) {   // 1 load per thread
        const int k0 = t << 5;
        int idx = tid;                      // B: 128 rows x 4 segs = 512
        int row = idx >> 2;
        int gseg = (idx & 3) ^ ((idx >> 3) & 3);
        __builtin_amdgcn_global_load_lds(
            (const __attribute__((address_space(1))) void*)(B + (size_t)(n0 + row) * K + k0 + gseg * 8),
            (__attribute__((address_space(3))) void*)(&Bs[buf][idx * 8]), 16, 0, 0);
    };

    f32x4 acc[4][4] = {};
    const int nkt = K >> 5;

    // prologue: queue order (oldest first) = A(0),B(0),A(1)
    STAGE_A(0, 0);
    __builtin_amdgcn_sched_barrier(0);
    STAGE_B(0, 0);
    __builtin_amdgcn_sched_barrier(0);
    STAGE_A(1, 1);
    __builtin_amdgcn_sched_barrier(0);

    int ca = 0, sa = 2;    // compute-A buffer, stage-A target
    for (int t = 0; t < nkt; ++t) {
        // drain A(t)+B(t); leave A(t+1)'s 2 loads in flight
        if (t + 1 < nkt) asm volatile("s_waitcnt vmcnt(2)" ::: "memory");
        else             asm volatile("s_waitcnt vmcnt(0)" ::: "memory");
        __builtin_amdgcn_s_barrier();
        __builtin_amdgcn_sched_barrier(0);
        // issue order matters for vmcnt counting: B(t+1) first, then A(t+2)
        if (t + 1 < nkt) STAGE_B((t + 1) & 1, t + 1);
        __builtin_amdgcn_sched_barrier(0);
        if (t + 2 < nkt) STAGE_A(sa, t + 2);
        __builtin_amdgcn_sched_barrier(0);

        bf16x8 af[4], bfr[4];
        #pragma unroll
        for (int mi = 0; mi < 4; ++mi) {
            int ra = wr + mi * 16 + qh;
            af[mi] = *reinterpret_cast<const bf16x8*>(&As[ca][ra * 32 + sw]);
        }
        #pragma unroll
        for (int ni = 0; ni < 4; ++ni) {
            int rb = wc + ni * 16 + qh;
            bfr[ni] = *reinterpret_cast<const bf16x8*>(&Bs[t & 1][rb * 32 + sw]);
        }
        __builtin_amdgcn_s_setprio(1);
        #pragma unroll
        for (int mi = 0; mi < 4; ++mi)
            #pragma unroll
            for (int ni = 0; ni < 4; ++ni)
                acc[mi][ni] = __builtin_amdgcn_mfma_f32_16x16x32_bf16(af[mi], bfr[ni], acc[mi][ni], 0, 0, 0);
        __builtin_amdgcn_s_setprio(0);

        ca = (ca == 2) ? 0 : ca + 1;
        sa = (sa == 2) ? 0 : sa + 1;
    }

    #pragma unroll
    for (int ni = 0; ni < 4; ++ni) {
        const int col = n0 + wc + ni * 16 + qh;
        #pragma unroll
        for (int mi = 0; mi < 4; ++mi) {
            #pragma unroll
            for (int r = 0; r < 4; ++r) {
                int row = m0 + wr + mi * 16 + (g << 2) + r;
                float v = acc[mi][ni][r];
                if constexpr (EPI == 1) {
                    Cout[(size_t)row * N + col] = (__bf16)v;
                } else {
                    Cout[(size_t)row * N + col] = (__bf16)gelu_fast(v);
                }
            }
        }
    }
}

// ---------------- MFMA window attention: one wave per (window, head) ----------------
// qkv is row-major [m][1152]: cols [0,384)=Q heads, [384,768)=K, [768,1152)=V;
// within each third, head hh occupies cols hh*32..hh*32+31. Row m = wi*64 + t.
__global__ __launch_bounds__(256) void k_attn(const __bf16* __restrict__ qkv,
                                              __bf16* __restrict__ AO)
{
    __shared__ __bf16 Pl[4][kT * kT];   // 8 KB per wave, XOR-swizzled P tile
    const int wave = threadIdx.x >> 6, lane = threadIdx.x & 63;
    const int pair = blockIdx.x * 4 + wave;          // 0..12287
    const int wi = pair / kNH, hh = pair - wi * kNH;
    const int g = lane >> 4, qh = lane & 15;

    const __bf16* Qp = qkv + (size_t)wi * 64 * kQKV + hh * kDH;   // row stride kQKV
    const __bf16* Kp = Qp + 384;
    const __bf16* Vp = Qp + 768;
    char* Pb = (char*)&Pl[wave][0];

    bf16x8 qa[4], kb[4];
    #pragma unroll
    for (int mi = 0; mi < 4; ++mi)
        qa[mi] = *reinterpret_cast<const bf16x8*>(Qp + (size_t)(mi * 16 + qh) * kQKV + g * 8);
    #pragma unroll
    for (int ni = 0; ni < 4; ++ni)
        kb[ni] = *reinterpret_cast<const bf16x8*>(Kp + (size_t)(ni * 16 + qh) * kQKV + g * 8);

    f32x4 s[4][4] = {};
    #pragma unroll
    for (int mi = 0; mi < 4; ++mi)
        #pragma unroll
        for (int ni = 0; ni < 4; ++ni)
            s[mi][ni] = __builtin_amdgcn_mfma_f32_16x16x32_bf16(qa[mi], kb[ni], s[mi][ni], 0, 0, 0);

    const float scale = 0.17677669529663687f;  // 32^-0.5
    float rmax[4][4], rsum[4][4];
    #pragma unroll
    for (int mi = 0; mi < 4; ++mi)
        #pragma unroll
        for (int r = 0; r < 4; ++r) {
            float a = fmaxf(fmaxf(s[mi][0][r], s[mi][1][r]), fmaxf(s[mi][2][r], s[mi][3][r]));
            #pragma unroll
            for (int st = 1; st < 16; st <<= 1) a = fmaxf(a, __shfl_xor(a, st));
            rmax[mi][r] = a;
        }
    #pragma unroll
    for (int mi = 0; mi < 4; ++mi)
        #pragma unroll
        for (int r = 0; r < 4; ++r) {
            float acc = 0.f;
            #pragma unroll
            for (int ni = 0; ni < 4; ++ni) {
                float p = __expf((s[mi][ni][r] - rmax[mi][r]) * scale);
                s[mi][ni][r] = p;
                acc += p;
            }
            #pragma unroll
            for (int st = 1; st < 16; st <<= 1) acc += __shfl_xor(acc, st);
            rsum[mi][r] = 1.0f / acc;
        }

    #pragma unroll
    for (int mi = 0; mi < 4; ++mi)
        #pragma unroll
        for (int ni = 0; ni < 4; ++ni)
            #pragma unroll
            for (int r = 0; r < 4; ++r) {
                int row = mi * 16 + g * 4 + r;
                int col = ni * 16 + qh;
                uint32 byte = (uint32)((row << 7) | (col << 1)) ^ (uint32)((row & 7) << 4);
                *reinterpret_cast<__bf16*>(Pb + byte) = (__bf16)s[mi][ni][r];
            }

    f32x4 o[4][2] = {};
    #pragma unroll
    for (int kk = 0; kk < 2; ++kk) {
        bf16x8 pa[4], vb[2];
        #pragma unroll
        for (int mi = 0; mi < 4; ++mi) {
            int row = mi * 16 + qh;
            uint32 byte = (uint32)((row << 7) | (kk << 6) | (g << 4)) ^ (uint32)((row & 7) << 4);
            pa[mi] = *reinterpret_cast<const bf16x8*>(Pb + byte);
        }
        #pragma unroll
        for (int n2 = 0; n2 < 2; ++n2) {
            __bf16 tmp[8];
            #pragma unroll
            for (int j = 0; j < 8; ++j)
                tmp[j] = Vp[(size_t)(kk * 32 + g * 8 + j) * kQKV + n2 * 16 + qh];
            vb[n2] = *reinterpret_cast<const bf16x8*>(tmp);
        }
        #pragma unroll
        for (int mi = 0; mi < 4; ++mi)
            #pragma unroll
            for (int n2 = 0; n2 < 2; ++n2)
                o[mi][n2] = __builtin_amdgcn_mfma_f32_16x16x32_bf16(pa[mi], vb[n2], o[mi][n2], 0, 0, 0);
    }

    #pragma unroll
    for (int mi = 0; mi < 4; ++mi)
        #pragma unroll
        for (int n2 = 0; n2 < 2; ++n2)
            #pragma unroll
            for (int r = 0; r < 4; ++r) {
                int row = mi * 16 + g * 4 + r;
                AO[((size_t)wi * 64 + row) * kC + hh * kDH + n2 * 16 + qh] =
                    (__bf16)(o[mi][n2][r] * rsum[mi][r]);
            }
}

// ---------------- LN(no-bias) + residual, window-order input (vectorized) ----------------
__global__ __launch_bounds__(256) void k_ln_res1(const __bf16* __restrict__ P,
                                                 const float* __restrict__ x,
                                                 const float* __restrict__ gamma,
                                                 __bf16* __restrict__ X1)
{
    const int wave = threadIdx.x >> 6, lane = threadIdx.x & 63;
    const int tok = blockIdx.x * 4 + wave;     // natural: b*4096 + h*64 + w
    const int b = tok >> 12, hw = tok & 4095, h = hw >> 6, w = hw & 63;
    const int m = (((b << 6) | ((h >> 3) << 3) | (w >> 3)) << 6) | (((h & 7) << 3) | (w & 7));

    const uint32* Pv = reinterpret_cast<const uint32*>(P + (size_t)m * kC);
    float p[6]; float sum = 0.f, sq = 0.f;
    #pragma unroll
    for (int i = 0; i < 3; ++i) {
        uint32 u = Pv[lane + i * 64];
        float a = bf_lo(u), bb = bf_hi(u);
        p[2 * i] = a; p[2 * i + 1] = bb;
        sum += a + bb; sq += a * a + bb * bb;
    }
    #pragma unroll
    for (int off = 32; off; off >>= 1) { sum += __shfl_xor(sum, off); sq += __shfl_xor(sq, off); }
    float mean = sum * (1.0f / kC);
    float var  = sq * (1.0f / kC) - mean * mean;
    float rs   = rsqrtf(var + 1e-5f);

    const float2* xv = reinterpret_cast<const float2*>(x + (size_t)tok * kC);
    const float2* gv = reinterpret_cast<const float2*>(gamma);
    uint32* Xv = reinterpret_cast<uint32*>(X1 + (size_t)tok * kC);
    #pragma unroll
    for (int i = 0; i < 3; ++i) {
        int idx = lane + i * 64;
        float2 xr = xv[idx];
        float2 gg = gv[idx];
        float v0 = xr.x + (p[2 * i]     - mean) * rs * gg.x;
        float v1 = xr.y + (p[2 * i + 1] - mean) * rs * gg.y;
        __bf16 t2[2] __attribute__((aligned(4)));
        t2[0] = (__bf16)v0; t2[1] = (__bf16)v1;
        Xv[idx] = *reinterpret_cast<uint32*>(t2);
    }
}

// ---------------- LN(no-bias) + residual, natural order, fp32 out (vectorized) ----------------
__global__ __launch_bounds__(256) void k_ln_res2(const __bf16* __restrict__ F,
                                                 const __bf16* __restrict__ X1,
                                                 const float* __restrict__ gamma,
                                                 float* __restrict__ out)
{
    const int wave = threadIdx.x >> 6, lane = threadIdx.x & 63;
    const size_t tok = blockIdx.x * 4 + wave;

    const uint32* Fv = reinterpret_cast<const uint32*>(F + tok * kC);
    float f[6]; float sum = 0.f, sq = 0.f;
    #pragma unroll
    for (int i = 0; i < 3; ++i) {
        uint32 u = Fv[lane + i * 64];
        float a = bf_lo(u), bb = bf_hi(u);
        f[2 * i] = a; f[2 * i + 1] = bb;
        sum += a + bb; sq += a * a + bb * bb;
    }
    #pragma unroll
    for (int off = 32; off; off >>= 1) { sum += __shfl_xor(sum, off); sq += __shfl_xor(sq, off); }
    float mean = sum * (1.0f / kC);
    float var  = sq * (1.0f / kC) - mean * mean;
    float rs   = rsqrtf(var + 1e-5f);

    const uint32* Xv = reinterpret_cast<const uint32*>(X1 + tok * kC);
    const float2* gv = reinterpret_cast<const float2*>(gamma);
    float2* ov = reinterpret_cast<float2*>(out + tok * kC);
    #pragma unroll
    for (int i = 0; i < 3; ++i) {
        int idx = lane + i * 64;
        uint32 xr = Xv[idx];
        float2 gg = gv[idx];
        float2 o2;
        o2.x = bf_lo(xr) + (f[2 * i]     - mean) * rs * gg.x;
        o2.y = bf_hi(xr) + (f[2 * i + 1] - mean) * rs * gg.y;
        ov[idx] = o2;
    }
}

extern "C" void kernel_launch(void* const* d_in, const int* in_sizes, int n_in,
                              void* d_out, int out_size, void* d_ws, size_t ws_size,
                              hipStream_t stream) {
    const float* x    = (const float*)d_in[0];
    const float* wqkv = (const float*)d_in[1];
    const float* wout = (const float*)d_in[2];
    const float* g_at = (const float*)d_in[3];
    const float* w1   = (const float*)d_in[4];
    const float* w2   = (const float*)d_in[5];
    const float* g_ff = (const float*)d_in[6];
    float* out = (float*)d_out;

    char* ws = (char*)d_ws;
    size_t off = 0;
    auto alloc = [&](size_t bytes) { size_t o = off; off += (bytes + 255) & ~(size_t)255; return o; };
    __bf16* WqkvT = (__bf16*)(ws + alloc((size_t)1152 * 384 * 2));
    __bf16* WoutT = (__bf16*)(ws + alloc((size_t)384 * 384 * 2));
    __bf16* W1T   = (__bf16*)(ws + alloc((size_t)1536 * 384 * 2));
    __bf16* W2T   = (__bf16*)(ws + alloc((size_t)384 * 1536 * 2));
    __bf16* R1    = (__bf16*)(ws + alloc((size_t)kNTOK * kDFF * 2));  // qkv rows (1152) / FFN hidden
    __bf16* R2    = (__bf16*)(ws + alloc((size_t)kNT * 2));           // Aw -> AO -> X1
    __bf16* R3    = (__bf16*)(ws + alloc((size_t)kNT * 2));           // P -> F

    // all four weight transposes, LDS-tiled (432 tiles of 64x64)
    k_transpose_all<<<dim3(432), 256, 0, stream>>>(wqkv, WqkvT, wout, WoutT, w1, W1T, w2, W2T);

    // shift2d + window partition
    k_shift_window<<<dim3(12288), 256, 0, stream>>>(x, R2);

    // qkv projection (plain row-major [m][1152] output): M=65536, N=1152, K=384
    k_gemm<1><<<dim3(256 * 9), 512, 0, stream>>>(R2, WqkvT, R1, 1152, 384, 9);

    // window attention (MFMA, reads interleaved qkv rows)
    k_attn<<<dim3(3072), 256, 0, stream>>>(R1, R2);

    // output projection: N=384, K=384
    k_gemm<1><<<dim3(256 * 3), 512, 0, stream>>>(R2, WoutT, R3, 384, 384, 3);

    // x1 = x + LN(attn)
    k_ln_res1<<<dim3(16384), 256, 0, stream>>>(R3, x, g_at, R2);

    // FFN up + gelu: N=1536, K=384
    k_gemm<2><<<dim3(256 * 12), 512, 0, stream>>>(R2, W1T, R1, 1536, 384, 12);

    // FFN down: N=384, K=1536
    k_gemm<1><<<dim3(256 * 3), 512, 0, stream>>>(R1, W2T, R3, 384, 1536, 3);

    // out = x1 + LN(f)
    k_ln_res2<<<dim3(16384), 256, 0, stream>>>(R3, R2, g_ff, out);
}